// Round 2
// baseline (134.236 us; speedup 1.0000x reference)
//
#include <hip/hip_runtime.h>

#define B_      2
#define C_      256
#define H_      96
#define W_      96
#define HW_     (H_ * W_)
#define P_      7
#define PP_     (P_ * P_)
#define NROIS_  512
#define SCALE_  0.0625f
#define TSTD_   0.1f

#define NGROUP_ 8                       // channel groups
#define GC_     (C_ / NGROUP_)          // 32 channels per group

// LDS patch: up to PATCH_MAX pixels of 32 bf16 channels, stored as 4
// channel-quad planes of 16-B entries.  Plane stride PSPIX_ = PATCH_MAX+2
// entries -> stride mod 32 banks = 8 words, so the 4 chq planes are bank-
// staggered and a tap wave (16 bins x 4 chq) lands ~2 lanes/bank (free).
#define PATCH_MAX 1120
#define PSPIX_    (PATCH_MAX + 2)

typedef float vf4 __attribute__((ext_vector_type(4)));

// f32 -> bf16 (round-to-nearest-even), as raw bits
__device__ __forceinline__ unsigned f2bf(float f) {
    union { float f; unsigned u; } x; x.f = f;
    return (x.u + 0x7fffu + ((x.u >> 16) & 1u)) >> 16;
}
__device__ __forceinline__ float bf_lo(unsigned u) {
    union { unsigned i; float f; } x; x.i = u << 16; return x.f;
}
__device__ __forceinline__ float bf_hi(unsigned u) {
    union { unsigned i; float f; } x; x.i = u & 0xffff0000u; return x.f;
}

// ---------------------------------------------------------------------------
// Pass 1 (unchanged, R6): f32 CHW -> bf16 group-planar [b][g][HW][32ch].
// ---------------------------------------------------------------------------
__global__ __launch_bounds__(256) void nchw_to_gp_bf16(const float* __restrict__ in,
                                                       ushort* __restrict__ out) {
    __shared__ float tile[32][36];          // [ch][px], stride 36: b128-aligned
    const int b   = blockIdx.z;
    const int g   = blockIdx.x & (NGROUP_ - 1);
    const int p0  = (blockIdx.x >> 3) * 32; // pixel tile origin
    const int c0  = g * 32;                 // channel tile origin
    const int tid = threadIdx.x;

    const float* src = in + (size_t)b * (C_ * HW_);
    ushort*      dst = out + ((size_t)(b * NGROUP_ + g) * HW_) * GC_;

    {
        const int cr = tid >> 3;            // 0..31 channel row
        const int pq = (tid & 7) * 4;       // pixel quad
        const vf4 v = __builtin_nontemporal_load(
            (const vf4*)&src[(size_t)(c0 + cr) * HW_ + p0 + pq]);
        *(vf4*)&tile[cr][pq] = v;
    }
    __syncthreads();
    {
        const int p  = tid >> 3;            // 0..31 pixel
        const int cq = (tid & 7) * 4;       // channel quad
        uint2 o;
        o.x = f2bf(tile[cq + 0][p]) | (f2bf(tile[cq + 1][p]) << 16);
        o.y = f2bf(tile[cq + 2][p]) | (f2bf(tile[cq + 3][p]) << 16);
        *(uint2*)&((unsigned*)dst)[(size_t)(p0 + p) * (GC_ / 2) + (cq >> 1)] = o;
    }
}

// ---------------------------------------------------------------------------
// Pass 2 (R8): LDS-patch bilinear taps.
// Theory: R6/R7 were bound by the L1-miss segment rate of ~4.2M scattered
// 64-B gather segments (~4 cyc each -> ~27 us), NOT by bytes/occupancy (R7's
// null result).  Each (n,g) block's 784 taps cover only the ROI's bbox patch
// (~19x19 px ~ 23 KB, 4.3x tap redundancy), so: compute the trans-dependent
// bbox (shared atomicMin/Max), stage the patch with ONE coalesced pass, and
// serve all taps from LDS.  Blocks with patch > PATCH_MAX px (~15%) take the
// R6 direct-global path (block-uniform branch).  LDS 78.5 KB -> 2 blocks/CU;
// launch_bounds(256,2) so regalloc isn't squeezed (LDS is the binding limit).
// ---------------------------------------------------------------------------
__global__ __launch_bounds__(256, 2) void dpsroi_pool7(const ushort* __restrict__ feat,
                                                       const float* __restrict__ rois,
                                                       const float* __restrict__ trans,
                                                       float* __restrict__ out) {
    __shared__ uint4 patch[4 * PSPIX_];     // 71,808 B: 4 chq planes
    __shared__ float sout[GC_ * PP_];       // 6,272 B, global layout
    __shared__ float ttab[2 * PP_];         // staged trans for this roi
    __shared__ int   bb[4];                 // xmin, xmax, ymin, ymax

    const int blk = blockIdx.x;
    const int g   = blk & (NGROUP_ - 1);    // static XCD affinity (xcd = bid%8)
    const int n   = blk >> 3;
    const int tid = threadIdx.x;
    const int bin = tid >> 2;               // 0..63 (49 active)
    const int chq = tid & 3;
    const int ch0 = chq * 8;                // 8 channels per lane

    if (tid < 2 * PP_) ttab[tid] = trans[n * (2 * PP_) + tid];
    if (tid == 0) { bb[0] = 1 << 30; bb[1] = -(1 << 30); bb[2] = 1 << 30; bb[3] = -(1 << 30); }

    // ROI geometry (block-uniform)
    const int   broi = (int)rois[n * 5 + 0];
    const float x1 = rintf(rois[n * 5 + 1]) * SCALE_ - 0.5f;
    const float y1 = rintf(rois[n * 5 + 2]) * SCALE_ - 0.5f;
    const float x2 = (rintf(rois[n * 5 + 3]) + 1.0f) * SCALE_ - 0.5f;
    const float y2 = (rintf(rois[n * 5 + 4]) + 1.0f) * SCALE_ - 0.5f;
    const float rw = fmaxf(x2 - x1, 0.1f);
    const float rh = fmaxf(y2 - y1, 0.1f);
    const float bin_w = rw * (1.0f / 7.0f);
    const float bin_h = rh * (1.0f / 7.0f);
    const float sub_w = bin_w * 0.5f;
    const float sub_h = bin_h * 0.5f;

    __syncthreads();                        // ttab + bb init ready

    float wstart = 0.f, hstart = 0.f;
    if (bin < PP_) {
        const int pi = bin / P_;
        const int pj = bin - pi * P_;
        const float tx = ttab[bin] * TSTD_;
        const float ty = ttab[PP_ + bin] * TSTD_;
        wstart = (float)pj * bin_w + x1 + tx * rw;
        hstart = (float)pi * bin_h + y1 + ty * rh;
        if (chq == 0) {
            // tap x-range for this bin: [floor(clamp(wstart)), ceil(clamp(wstart+sub_w))]
            const int xlo = (int)floorf(fminf(fmaxf(wstart, 0.0f), (float)(W_ - 1)));
            const int xhi = (int)ceilf (fminf(fmaxf(wstart + sub_w, 0.0f), (float)(W_ - 1)));
            const int ylo = (int)floorf(fminf(fmaxf(hstart, 0.0f), (float)(H_ - 1)));
            const int yhi = (int)ceilf (fminf(fmaxf(hstart + sub_h, 0.0f), (float)(H_ - 1)));
            atomicMin(&bb[0], xlo); atomicMax(&bb[1], xhi);
            atomicMin(&bb[2], ylo); atomicMax(&bb[3], yhi);
        }
    }
    __syncthreads();                        // bbox final

    const int bx0 = bb[0], bx1 = bb[1], by0 = bb[2], by1 = bb[3];
    const int pw = bx1 - bx0 + 1;
    const int ph = by1 - by0 + 1;
    const bool use_patch = (pw * ph <= PATCH_MAX);

    const ushort* fb0 = feat + ((size_t)(broi * NGROUP_ + g) * HW_) * GC_;

    if (use_patch) {
        // one coalesced pass: rows of pw*64 B, de-interleaved into 4 chq planes
        const uint4* src = (const uint4*)fb0;
        const int pw4   = pw * 4;
        const int total = ph * pw4;
        for (int q = tid; q < total; q += 256) {
            const int py  = q / pw4;
            const int r   = q - py * pw4;   // = pxl*4 + cq
            const int pxl = r >> 2;
            const int cq  = r & 3;
            patch[cq * PSPIX_ + py * pw + pxl] = src[((by0 + py) * W_ + bx0) * 4 + r];
        }
        __syncthreads();                    // patch ready
    }

    if (bin < PP_) {
        // ---- phase 1: all 16 weights + tap coords ----
        float wt[16];
        int xs0[4], xs1[4], ys0[4], ys1[4];
        int cnt = 0;
#pragma unroll
        for (int s = 0; s < 4; ++s) {
            const float w = wstart + (float)(s & 1) * sub_w;
            const float h = hstart + (float)(s >> 1) * sub_h;
            const bool valid = (w >= -0.5f) & (w <= (float)W_ - 0.5f) &
                               (h >= -0.5f) & (h <= (float)H_ - 0.5f);
            cnt += valid ? 1 : 0;
            const float vf = valid ? 1.0f : 0.0f;
            const float wc  = fminf(fmaxf(w, 0.0f), (float)(W_ - 1));
            const float hc  = fminf(fmaxf(h, 0.0f), (float)(H_ - 1));
            const float x0f = floorf(wc), y0f = floorf(hc);
            const float dx  = wc - x0f,   dy  = hc - y0f;
            xs0[s] = (int)x0f;            ys0[s] = (int)y0f;
            xs1[s] = (int)ceilf(wc);      ys1[s] = (int)ceilf(hc);
            wt[4 * s + 0] = vf * (1.0f - dx) * (1.0f - dy);
            wt[4 * s + 1] = vf * dx * (1.0f - dy);
            wt[4 * s + 2] = vf * (1.0f - dx) * dy;
            wt[4 * s + 3] = vf * dx * dy;
        }

        // ---- phase 2: 16 taps, from LDS patch or direct global ----
        uint4 v[16];
        if (use_patch) {
            const uint4* pp = patch + chq * PSPIX_;
#pragma unroll
            for (int s = 0; s < 4; ++s) {
                const int r0 = (ys0[s] - by0) * pw - bx0;
                const int r1 = (ys1[s] - by0) * pw - bx0;
                v[4 * s + 0] = pp[r0 + xs0[s]];
                v[4 * s + 1] = pp[r0 + xs1[s]];
                v[4 * s + 2] = pp[r1 + xs0[s]];
                v[4 * s + 3] = pp[r1 + xs1[s]];
            }
        } else {
            const ushort* fbq = fb0 + ch0;
#pragma unroll
            for (int s = 0; s < 4; ++s) {
                v[4 * s + 0] = *(const uint4*)(fbq + (size_t)(ys0[s] * W_ + xs0[s]) * GC_);
                v[4 * s + 1] = *(const uint4*)(fbq + (size_t)(ys0[s] * W_ + xs1[s]) * GC_);
                v[4 * s + 2] = *(const uint4*)(fbq + (size_t)(ys1[s] * W_ + xs0[s]) * GC_);
                v[4 * s + 3] = *(const uint4*)(fbq + (size_t)(ys1[s] * W_ + xs1[s]) * GC_);
            }
        }

        // ---- phase 3: unpack + FMA in load order ----
        float acc[8] = {0.f, 0.f, 0.f, 0.f, 0.f, 0.f, 0.f, 0.f};
#pragma unroll
        for (int i = 0; i < 16; ++i) {
            const float wgt = wt[i];
            acc[0] += wgt * bf_lo(v[i].x);
            acc[1] += wgt * bf_hi(v[i].x);
            acc[2] += wgt * bf_lo(v[i].y);
            acc[3] += wgt * bf_hi(v[i].y);
            acc[4] += wgt * bf_lo(v[i].z);
            acc[5] += wgt * bf_hi(v[i].z);
            acc[6] += wgt * bf_lo(v[i].w);
            acc[7] += wgt * bf_hi(v[i].w);
        }

        const float inv = (cnt > 0) ? (1.0f / (float)cnt) : 0.0f;
#pragma unroll
        for (int j = 0; j < 8; ++j)
            sout[(ch0 + j) * PP_ + bin] = acc[j] * inv;
    }

    __syncthreads();
    // out[n, g*32 : (g+1)*32, :, :] contiguous: 32*49 = 1568 floats
    float* outn = out + ((size_t)n * C_ + g * GC_) * PP_;
    for (int f = tid; f < GC_ * PP_; f += 256)
        __builtin_nontemporal_store(sout[f], &outn[f]);
}

extern "C" void kernel_launch(void* const* d_in, const int* in_sizes, int n_in,
                              void* d_out, int out_size, void* d_ws, size_t ws_size,
                              hipStream_t stream) {
    const float* feat  = (const float*)d_in[0];   // (2,256,96,96) f32
    const float* rois  = (const float*)d_in[1];   // (512,5)
    const float* trans = (const float*)d_in[2];   // (512,2,7,7)
    float* out = (float*)d_out;                   // (512,256,7,7) f32

    ushort* gp = (ushort*)d_ws;                   // bf16 group-planar, 9.4 MB
    dim3 tb(256);
    dim3 tg((HW_ / 32) * NGROUP_, 1, B_);         // g = blockIdx.x & 7
    nchw_to_gp_bf16<<<tg, tb, 0, stream>>>(feat, gp);
    dpsroi_pool7<<<NROIS_ * NGROUP_, 256, 0, stream>>>(gp, rois, trans, out);
}

// Round 3
// 128.380 us; speedup vs baseline: 1.0456x; 1.0456x over previous
//
#include <hip/hip_runtime.h>

#define B_      2
#define C_      256
#define H_      96
#define W_      96
#define HW_     (H_ * W_)
#define P_      7
#define PP_     (P_ * P_)
#define NROIS_  512
#define SCALE_  0.0625f
#define TSTD_   0.1f

#define NGROUP_ 8                       // channel groups
#define GC_     (C_ / NGROUP_)          // 32 channels per group

typedef float vf4 __attribute__((ext_vector_type(4)));

// f32 -> bf16 (round-to-nearest-even), as raw bits
__device__ __forceinline__ unsigned f2bf(float f) {
    union { float f; unsigned u; } x; x.f = f;
    return (x.u + 0x7fffu + ((x.u >> 16) & 1u)) >> 16;
}
__device__ __forceinline__ float bf_lo(unsigned u) {
    union { unsigned i; float f; } x; x.i = u << 16; return x.f;
}
__device__ __forceinline__ float bf_hi(unsigned u) {
    union { unsigned i; float f; } x; x.i = u & 0xffff0000u; return x.f;
}

// ---------------------------------------------------------------------------
// Pass 1 (unchanged R6): f32 CHW -> bf16 group-planar [b][g][HW][32ch].
// ---------------------------------------------------------------------------
__global__ __launch_bounds__(256) void nchw_to_gp_bf16(const float* __restrict__ in,
                                                       ushort* __restrict__ out) {
    __shared__ float tile[32][36];          // [ch][px], stride 36: b128-aligned
    const int b   = blockIdx.z;
    const int g   = blockIdx.x & (NGROUP_ - 1);
    const int p0  = (blockIdx.x >> 3) * 32; // pixel tile origin
    const int c0  = g * 32;                 // channel tile origin
    const int tid = threadIdx.x;

    const float* src = in + (size_t)b * (C_ * HW_);
    ushort*      dst = out + ((size_t)(b * NGROUP_ + g) * HW_) * GC_;

    {
        const int cr = tid >> 3;            // 0..31 channel row
        const int pq = (tid & 7) * 4;       // pixel quad
        const vf4 v = __builtin_nontemporal_load(
            (const vf4*)&src[(size_t)(c0 + cr) * HW_ + p0 + pq]);
        *(vf4*)&tile[cr][pq] = v;
    }
    __syncthreads();
    {
        const int p  = tid >> 3;            // 0..31 pixel
        const int cq = (tid & 7) * 4;       // channel quad
        uint2 o;
        o.x = f2bf(tile[cq + 0][p]) | (f2bf(tile[cq + 1][p]) << 16);
        o.y = f2bf(tile[cq + 2][p]) | (f2bf(tile[cq + 3][p]) << 16);
        *(uint2*)&((unsigned*)dst)[(size_t)(p0 + p) * (GC_ / 2) + (cq >> 1)] = o;
    }
}

// ---------------------------------------------------------------------------
// Pass 2 (R9): direct-gather (R6 structure) rebuilt for MAX OCCUPANCY.
// Counters (R8 run) showed pass 2 is L2-latency-bound: FETCH 5 MB (L2-
// resident), HBM 6%, VALUBusy 30%, bank conflicts nil — the limiter is
// outstanding-miss concurrency, and every prior variant (VGPR 85..128) sat
// in the 4-waves/SIMD occupancy bin.  This version processes the 16 taps as
// 4 per-sample batches (v[4] not v[16], wt/ofs[4] not [16], acc-carried) to
// fit <=64 VGPR; __launch_bounds__(256, 8) pins 8 waves/SIMD = 32 waves/CU
// = 2x R6's concurrency.  LDS is only sout+ttab (6.7 KB) -> 8 blocks/CU.
// The unrolled sample loop still lets the scheduler hoist next-sample loads
// while the current sample's FMAs run.
// ---------------------------------------------------------------------------
__global__ __launch_bounds__(256, 8) void dpsroi_pool7(const ushort* __restrict__ feat,
                                                       const float* __restrict__ rois,
                                                       const float* __restrict__ trans,
                                                       float* __restrict__ out) {
    __shared__ float sout[GC_ * PP_];       // 32*49*4 = 6272 B, global layout
    __shared__ float ttab[2 * PP_];         // staged trans for this roi

    const int blk = blockIdx.x;
    const int g   = blk & (NGROUP_ - 1);    // static XCD affinity
    const int n   = blk >> 3;
    const int tid = threadIdx.x;
    const int bin = tid >> 2;               // 0..63 (49 active)
    const int ch0 = (tid & 3) * 8;          // 8 channels per lane

    if (tid < 2 * PP_) ttab[tid] = trans[n * (2 * PP_) + tid];

    // ROI geometry (block-uniform -> scalar regs)
    const int   broi = (int)rois[n * 5 + 0];
    const float x1 = rintf(rois[n * 5 + 1]) * SCALE_ - 0.5f;
    const float y1 = rintf(rois[n * 5 + 2]) * SCALE_ - 0.5f;
    const float x2 = (rintf(rois[n * 5 + 3]) + 1.0f) * SCALE_ - 0.5f;
    const float y2 = (rintf(rois[n * 5 + 4]) + 1.0f) * SCALE_ - 0.5f;
    const float rw = fmaxf(x2 - x1, 0.1f);
    const float rh = fmaxf(y2 - y1, 0.1f);
    const float bin_w = rw * (1.0f / 7.0f);
    const float bin_h = rh * (1.0f / 7.0f);
    const float sub_w = bin_w * 0.5f;
    const float sub_h = bin_h * 0.5f;

    __syncthreads();                        // ttab ready

    const ushort* fb = feat + ((size_t)(broi * NGROUP_ + g) * HW_) * GC_ + ch0;

    if (bin < PP_) {
        const int pi = bin / P_;
        const int pj = bin - pi * P_;
        const float tx = ttab[bin] * TSTD_;
        const float ty = ttab[PP_ + bin] * TSTD_;
        const float wstart = (float)pj * bin_w + x1 + tx * rw;
        const float hstart = (float)pi * bin_h + y1 + ty * rh;

        float acc[8] = {0.f, 0.f, 0.f, 0.f, 0.f, 0.f, 0.f, 0.f};
        int   cnt = 0;

#pragma unroll
        for (int s = 0; s < 4; ++s) {
            const float w = wstart + (float)(s & 1) * sub_w;
            const float h = hstart + (float)(s >> 1) * sub_h;
            const bool valid = (w >= -0.5f) & (w <= (float)W_ - 0.5f) &
                               (h >= -0.5f) & (h <= (float)H_ - 0.5f);
            cnt += valid ? 1 : 0;
            const float vf = valid ? 1.0f : 0.0f;
            const float wc  = fminf(fmaxf(w, 0.0f), (float)(W_ - 1));
            const float hc  = fminf(fmaxf(h, 0.0f), (float)(H_ - 1));
            const float x0f = floorf(wc), y0f = floorf(hc);
            const float dx  = wc - x0f,   dy  = hc - y0f;
            const int   x0  = (int)x0f,   y0  = (int)y0f;
            const int   xp  = (int)ceilf(wc), yp = (int)ceilf(hc);

            // issue the 4 corner gathers first (weights compute under vmcnt)
            const uint4 v0 = *(const uint4*)(fb + (size_t)(y0 * W_ + x0) * GC_);
            const uint4 v1 = *(const uint4*)(fb + (size_t)(y0 * W_ + xp) * GC_);
            const uint4 v2 = *(const uint4*)(fb + (size_t)(yp * W_ + x0) * GC_);
            const uint4 v3 = *(const uint4*)(fb + (size_t)(yp * W_ + xp) * GC_);

            const float w00 = vf * (1.0f - dx) * (1.0f - dy);
            const float w01 = vf * dx * (1.0f - dy);
            const float w10 = vf * (1.0f - dx) * dy;
            const float w11 = vf * dx * dy;

            acc[0] += w00 * bf_lo(v0.x); acc[1] += w00 * bf_hi(v0.x);
            acc[2] += w00 * bf_lo(v0.y); acc[3] += w00 * bf_hi(v0.y);
            acc[4] += w00 * bf_lo(v0.z); acc[5] += w00 * bf_hi(v0.z);
            acc[6] += w00 * bf_lo(v0.w); acc[7] += w00 * bf_hi(v0.w);

            acc[0] += w01 * bf_lo(v1.x); acc[1] += w01 * bf_hi(v1.x);
            acc[2] += w01 * bf_lo(v1.y); acc[3] += w01 * bf_hi(v1.y);
            acc[4] += w01 * bf_lo(v1.z); acc[5] += w01 * bf_hi(v1.z);
            acc[6] += w01 * bf_lo(v1.w); acc[7] += w01 * bf_hi(v1.w);

            acc[0] += w10 * bf_lo(v2.x); acc[1] += w10 * bf_hi(v2.x);
            acc[2] += w10 * bf_lo(v2.y); acc[3] += w10 * bf_hi(v2.y);
            acc[4] += w10 * bf_lo(v2.z); acc[5] += w10 * bf_hi(v2.z);
            acc[6] += w10 * bf_lo(v2.w); acc[7] += w10 * bf_hi(v2.w);

            acc[0] += w11 * bf_lo(v3.x); acc[1] += w11 * bf_hi(v3.x);
            acc[2] += w11 * bf_lo(v3.y); acc[3] += w11 * bf_hi(v3.y);
            acc[4] += w11 * bf_lo(v3.z); acc[5] += w11 * bf_hi(v3.z);
            acc[6] += w11 * bf_lo(v3.w); acc[7] += w11 * bf_hi(v3.w);
        }

        const float inv = (cnt > 0) ? (1.0f / (float)cnt) : 0.0f;
#pragma unroll
        for (int j = 0; j < 8; ++j)
            sout[(ch0 + j) * PP_ + bin] = acc[j] * inv;
    }

    __syncthreads();
    // out[n, g*32 : (g+1)*32, :, :] contiguous: 32*49 = 1568 floats
    float* outn = out + ((size_t)n * C_ + g * GC_) * PP_;
    for (int f = tid; f < GC_ * PP_; f += 256)
        __builtin_nontemporal_store(sout[f], &outn[f]);
}

extern "C" void kernel_launch(void* const* d_in, const int* in_sizes, int n_in,
                              void* d_out, int out_size, void* d_ws, size_t ws_size,
                              hipStream_t stream) {
    const float* feat  = (const float*)d_in[0];   // (2,256,96,96) f32
    const float* rois  = (const float*)d_in[1];   // (512,5)
    const float* trans = (const float*)d_in[2];   // (512,2,7,7)
    float* out = (float*)d_out;                   // (512,256,7,7) f32

    ushort* gp = (ushort*)d_ws;                   // bf16 group-planar, 9.4 MB
    dim3 tb(256);
    dim3 tg((HW_ / 32) * NGROUP_, 1, B_);         // g = blockIdx.x & 7
    nchw_to_gp_bf16<<<tg, tb, 0, stream>>>(feat, gp);
    dpsroi_pool7<<<NROIS_ * NGROUP_, 256, 0, stream>>>(gp, rois, trans, out);
}

// Round 4
// 99.177 us; speedup vs baseline: 1.3535x; 1.2945x over previous
//
#include <hip/hip_runtime.h>

#define B_      2
#define C_      256
#define H_      96
#define W_      96
#define HW_     (H_ * W_)
#define P_      7
#define PP_     (P_ * P_)
#define NROIS_  512
#define SCALE_  0.0625f
#define TSTD_   0.1f

#define NGROUP_ 8                       // channel groups
#define GC_     (C_ / NGROUP_)          // 32 channels per group

typedef float vf4 __attribute__((ext_vector_type(4)));

// f32 -> bf16 (round-to-nearest-even), as raw bits
__device__ __forceinline__ unsigned f2bf(float f) {
    union { float f; unsigned u; } x; x.f = f;
    return (x.u + 0x7fffu + ((x.u >> 16) & 1u)) >> 16;
}
__device__ __forceinline__ float bf_lo(unsigned u) {
    union { unsigned i; float f; } x; x.i = u << 16; return x.f;
}
__device__ __forceinline__ float bf_hi(unsigned u) {
    union { unsigned i; float f; } x; x.i = u & 0xffff0000u; return x.f;
}

// ---------------------------------------------------------------------------
// Pass 1 (unchanged R6): f32 CHW -> bf16 group-planar [b][g][HW][32ch].
// ---------------------------------------------------------------------------
__global__ __launch_bounds__(256) void nchw_to_gp_bf16(const float* __restrict__ in,
                                                       ushort* __restrict__ out) {
    __shared__ float tile[32][36];          // [ch][px], stride 36: b128-aligned
    const int b   = blockIdx.z;
    const int g   = blockIdx.x & (NGROUP_ - 1);
    const int p0  = (blockIdx.x >> 3) * 32; // pixel tile origin
    const int c0  = g * 32;                 // channel tile origin
    const int tid = threadIdx.x;

    const float* src = in + (size_t)b * (C_ * HW_);
    ushort*      dst = out + ((size_t)(b * NGROUP_ + g) * HW_) * GC_;

    {
        const int cr = tid >> 3;            // 0..31 channel row
        const int pq = (tid & 7) * 4;       // pixel quad
        const vf4 v = __builtin_nontemporal_load(
            (const vf4*)&src[(size_t)(c0 + cr) * HW_ + p0 + pq]);
        *(vf4*)&tile[cr][pq] = v;
    }
    __syncthreads();
    {
        const int p  = tid >> 3;            // 0..31 pixel
        const int cq = (tid & 7) * 4;       // channel quad
        uint2 o;
        o.x = f2bf(tile[cq + 0][p]) | (f2bf(tile[cq + 1][p]) << 16);
        o.y = f2bf(tile[cq + 2][p]) | (f2bf(tile[cq + 3][p]) << 16);
        *(uint2*)&((unsigned*)dst)[(size_t)(p0 + p) * (GC_ / 2) + (cq >> 1)] = o;
    }
}

// ---------------------------------------------------------------------------
// Pass 2 (R10): clean occupancy test.
// R9's launch_bounds(256,8) forced VGPR=32 -> scratch SPILLS (WRITE 117.9 MB
// vs 25.1 MB output, FETCH 59.6 MB) — the occupancy theory was never tested.
// This version: direct gathers in two sample-PAIR batches (8 uint4 in flight
// = 32 data VGPRs; + acc[8] + temps ~ 70 total) under launch_bounds(256,6):
// VGPR cap ~85 -> NO spill, 6 waves/SIMD = 24 waves/CU (1.5x R6's 16).
// Decision rule: pass2 <= 32 us -> concurrency-bound, push occupancy more;
// pass2 ~= 40 us -> per-CU L1-miss service wall confirmed (structural).
// ---------------------------------------------------------------------------
__global__ __launch_bounds__(256, 6) void dpsroi_pool7(const ushort* __restrict__ feat,
                                                       const float* __restrict__ rois,
                                                       const float* __restrict__ trans,
                                                       float* __restrict__ out) {
    __shared__ float sout[GC_ * PP_];       // 32*49*4 = 6272 B, global layout
    __shared__ float ttab[2 * PP_];         // staged trans for this roi

    const int blk = blockIdx.x;
    const int g   = blk & (NGROUP_ - 1);    // static XCD affinity
    const int n   = blk >> 3;
    const int tid = threadIdx.x;
    const int bin = tid >> 2;               // 0..63 (49 active)
    const int ch0 = (tid & 3) * 8;          // 8 channels per lane

    if (tid < 2 * PP_) ttab[tid] = trans[n * (2 * PP_) + tid];

    // ROI geometry (block-uniform -> scalar regs)
    const int   broi = (int)rois[n * 5 + 0];
    const float x1 = rintf(rois[n * 5 + 1]) * SCALE_ - 0.5f;
    const float y1 = rintf(rois[n * 5 + 2]) * SCALE_ - 0.5f;
    const float x2 = (rintf(rois[n * 5 + 3]) + 1.0f) * SCALE_ - 0.5f;
    const float y2 = (rintf(rois[n * 5 + 4]) + 1.0f) * SCALE_ - 0.5f;
    const float rw = fmaxf(x2 - x1, 0.1f);
    const float rh = fmaxf(y2 - y1, 0.1f);
    const float bin_w = rw * (1.0f / 7.0f);
    const float bin_h = rh * (1.0f / 7.0f);
    const float sub_w = bin_w * 0.5f;
    const float sub_h = bin_h * 0.5f;

    __syncthreads();                        // ttab ready

    const ushort* fb = feat + ((size_t)(broi * NGROUP_ + g) * HW_) * GC_ + ch0;

    if (bin < PP_) {
        const int pi = bin / P_;
        const int pj = bin - pi * P_;
        const float tx = ttab[bin] * TSTD_;
        const float ty = ttab[PP_ + bin] * TSTD_;
        const float wstart = (float)pj * bin_w + x1 + tx * rw;
        const float hstart = (float)pi * bin_h + y1 + ty * rh;

        float acc[8] = {0.f, 0.f, 0.f, 0.f, 0.f, 0.f, 0.f, 0.f};
        int   cnt = 0;

#pragma unroll
        for (int sp = 0; sp < 2; ++sp) {    // sample pairs: (2*sp, 2*sp+1)
            // ---- geometry + offsets for both samples of the pair ----
            float wt[8];
            int   ofs[8];
#pragma unroll
            for (int t = 0; t < 2; ++t) {
                const int s = 2 * sp + t;
                const float w = wstart + (float)(s & 1) * sub_w;
                const float h = hstart + (float)(s >> 1) * sub_h;
                const bool valid = (w >= -0.5f) & (w <= (float)W_ - 0.5f) &
                                   (h >= -0.5f) & (h <= (float)H_ - 0.5f);
                cnt += valid ? 1 : 0;
                const float vf = valid ? 1.0f : 0.0f;
                const float wc  = fminf(fmaxf(w, 0.0f), (float)(W_ - 1));
                const float hc  = fminf(fmaxf(h, 0.0f), (float)(H_ - 1));
                const float x0f = floorf(wc), y0f = floorf(hc);
                const float dx  = wc - x0f,   dy  = hc - y0f;
                const int   x0  = (int)x0f,   y0  = (int)y0f;
                const int   xp  = (int)ceilf(wc), yp = (int)ceilf(hc);
                wt[4 * t + 0] = vf * (1.0f - dx) * (1.0f - dy);
                wt[4 * t + 1] = vf * dx * (1.0f - dy);
                wt[4 * t + 2] = vf * (1.0f - dx) * dy;
                wt[4 * t + 3] = vf * dx * dy;
                ofs[4 * t + 0] = y0 * W_ + x0;
                ofs[4 * t + 1] = y0 * W_ + xp;
                ofs[4 * t + 2] = yp * W_ + x0;
                ofs[4 * t + 3] = yp * W_ + xp;
            }

            // ---- 8 gathers in flight ----
            uint4 v[8];
#pragma unroll
            for (int i = 0; i < 8; ++i)
                v[i] = *(const uint4*)(fb + (size_t)ofs[i] * GC_);

            // ---- unpack + FMA in load order ----
#pragma unroll
            for (int i = 0; i < 8; ++i) {
                const float wgt = wt[i];
                acc[0] += wgt * bf_lo(v[i].x);
                acc[1] += wgt * bf_hi(v[i].x);
                acc[2] += wgt * bf_lo(v[i].y);
                acc[3] += wgt * bf_hi(v[i].y);
                acc[4] += wgt * bf_lo(v[i].z);
                acc[5] += wgt * bf_hi(v[i].z);
                acc[6] += wgt * bf_lo(v[i].w);
                acc[7] += wgt * bf_hi(v[i].w);
            }
        }

        const float inv = (cnt > 0) ? (1.0f / (float)cnt) : 0.0f;
#pragma unroll
        for (int j = 0; j < 8; ++j)
            sout[(ch0 + j) * PP_ + bin] = acc[j] * inv;
    }

    __syncthreads();
    // out[n, g*32 : (g+1)*32, :, :] contiguous: 32*49 = 1568 floats
    float* outn = out + ((size_t)n * C_ + g * GC_) * PP_;
    for (int f = tid; f < GC_ * PP_; f += 256)
        __builtin_nontemporal_store(sout[f], &outn[f]);
}

extern "C" void kernel_launch(void* const* d_in, const int* in_sizes, int n_in,
                              void* d_out, int out_size, void* d_ws, size_t ws_size,
                              hipStream_t stream) {
    const float* feat  = (const float*)d_in[0];   // (2,256,96,96) f32
    const float* rois  = (const float*)d_in[1];   // (512,5)
    const float* trans = (const float*)d_in[2];   // (512,2,7,7)
    float* out = (float*)d_out;                   // (512,256,7,7) f32

    ushort* gp = (ushort*)d_ws;                   // bf16 group-planar, 9.4 MB
    dim3 tb(256);
    dim3 tg((HW_ / 32) * NGROUP_, 1, B_);         // g = blockIdx.x & 7
    nchw_to_gp_bf16<<<tg, tb, 0, stream>>>(feat, gp);
    dpsroi_pool7<<<NROIS_ * NGROUP_, 256, 0, stream>>>(gp, rois, trans, out);
}